// Round 13
// baseline (54.501 us; speedup 1.0000x reference)
//
#include <hip/hip_runtime.h>
#include <hip/hip_bf16.h>

// SPP patch extraction, fused single-launch, persistent blocks.
// feat (512,48,48) fp32; scales {4,6,8,10,12,14,16}, stride-2 SxS windows,
// adaptive max pool 7x7 -> (ny*nx, 512*49) per scale, concatenated.
//
// R13 = R10's per-unit structure (P2 y-binned rp; one barrier; wave-
// autonomous emit with owb float4 staging + dwordx4 stores) wrapped in a
// PERSISTENT grid-stride loop: grid = 2048 blocks (= max co-resident),
// units u = bid + k*2048 over the 8960 (scale, chunk, iy) units in
// heavy-first order. Round-robin unit assignment gives each block a
// balanced mix of heavy/light scales -> tail quantization drops from
// ~half a block round (~6 us) to ~half a unit (~1.5 us).
// One __syncthreads per unit boundary protects rp reuse.

#define HW 48
#define CSTR (HW * HW)   // 2304
#define POOL 7
#define PE 25088         // 512*49 elems per patch
#define CH 8             // channels per block
#define RPS 50           // rp row stride (floats)
#define NUNITS 8960
#define NBLK 2048

constexpr int cdiv7(int x) { return (x + 6) / 7; }
constexpr int nyf(int S) { return (HW - S) / 2 + 1; }
constexpr int max_bin(int S) {
    int m = 0;
    for (int i = 0; i < POOL; ++i) {
        int a = (i * S) / POOL, b = cdiv7((i + 1) * S);
        if (b - a > m) m = b - a;
    }
    return m;
}

template <int S>
__device__ __forceinline__ void run_scale(int b, const float* __restrict__ feat,
                                          float* __restrict__ outp,
                                          float* rp, float* owb) {
    constexpr int NX = nyf(S);
    constexpr int MB = max_bin(S);
    const int tid = threadIdx.x;
    const int iy = b >> 6;           // 64 chunks
    const int c0 = (b & 63) * CH;
    const int y0 = iy * 2;

    // ---- P2: rp[row][x] = y-binned max, float2, direct from cache ----
    const float* fb = feat + (size_t)c0 * CSTR + y0 * HW;
    for (int t = tid; t < CH * POOL * (HW / 2); t += 256) {   // 1344
        int c = t / (POOL * 24);
        int rem = t - c * (POOL * 24);
        int py = rem / 24;
        int xl = rem - py * 24;                               // x = 2*xl
        int ay = (py * S) / POOL;
        int szy = cdiv7((py + 1) * S) - ay;
        const float* wb = fb + c * CSTR + ay * HW + 2 * xl;
        float2 m = *(const float2*)wb;
#pragma unroll
        for (int r = 1; r < MB; ++r) {
            float2 v = *(const float2*)(wb + min(r, szy - 1) * HW);
            m.x = fmaxf(m.x, v.x);
            m.y = fmaxf(m.y, v.y);
        }
        *(float2*)(rp + (c * POOL + py) * RPS + 2 * xl) = m;
    }
    __syncthreads();                 // rp ready

    // ---- wave-autonomous emit ----
    const int wv = tid >> 6;
    const int lane = tid & 63;
    float* myout = owb + wv * 392;   // private per-wave staging
    float* obase = outp + (size_t)iy * NX * PE + (size_t)c0 * 49;

    for (int ix = wv; ix < NX; ix += 4) {
        // P3: lanes 0..55 = rows (c*7+py); all bin indices compile-time
        if (lane < 56) {
            const float* v = rp + lane * RPS + 2 * ix;   // 8B-aligned
            float x[S];
#pragma unroll
            for (int k = 0; k < S / 2; ++k) {
                float2 p = *(const float2*)(v + 2 * k);
                x[2 * k] = p.x;
                x[2 * k + 1] = p.y;
            }
            float* ob = myout + lane * 7;                // output order
#pragma unroll
            for (int px = 0; px < POOL; ++px) {
                int ax = (px * S) / POOL;                // compile-time
                int bx = cdiv7((px + 1) * S);
                float m = x[ax];
#pragma unroll
                for (int k = ax + 1; k < bx; ++k) m = fmaxf(m, x[k]);
                ob[px] = m;
            }
        }
        asm volatile("" ::: "memory");  // keep P3 writes before P4 reads
        // P4: 98 float4 -> dense coalesced dwordx4 stores
        float* od = obase + (size_t)ix * PE;
        {
            float4 vv = *(const float4*)(myout + 4 * lane);
            *(float4*)(od + 4 * lane) = vv;
            int k2 = lane + 64;
            if (k2 < 98) {
                float4 v2 = *(const float4*)(myout + 4 * k2);
                *(float4*)(od + 4 * k2) = v2;
            }
        }
        asm volatile("" ::: "memory");  // keep P4 reads before next P3 writes
    }
}

__global__ __launch_bounds__(256) void spp_fused(const float* __restrict__ feat,
                                                 float* __restrict__ out) {
    __shared__ float rp[CH * POOL * RPS];        // 11.2 KB
    __shared__ __align__(16) float owb[4 * 392]; // 6.3 KB (per-wave slices)
    // Heavy-first unit order: S=16,14,12,10,8,6,4; output offsets in scale order.
    for (int u = blockIdx.x; u < NUNITS; u += NBLK) {
        if (u < 1088)      run_scale<16>(u,        feat, out + (size_t)2539 * PE, rp, owb);
        else if (u < 2240) run_scale<14>(u - 1088, feat, out + (size_t)2215 * PE, rp, owb);
        else if (u < 3456) run_scale<12>(u - 2240, feat, out + (size_t)1854 * PE, rp, owb);
        else if (u < 4736) run_scale<10>(u - 3456, feat, out + (size_t)1454 * PE, rp, owb);
        else if (u < 6080) run_scale<8>(u - 4736,  feat, out + (size_t)1013 * PE, rp, owb);
        else if (u < 7488) run_scale<6>(u - 6080,  feat, out + (size_t)529  * PE, rp, owb);
        else               run_scale<4>(u - 7488,  feat, out,                     rp, owb);
        __syncthreads();   // all waves done with rp before next unit's P2
    }
}

extern "C" void kernel_launch(void* const* d_in, const int* in_sizes, int n_in,
                              void* d_out, int out_size, void* d_ws, size_t ws_size,
                              hipStream_t stream) {
    const float* feat = (const float*)d_in[0];
    float* out = (float*)d_out;
    spp_fused<<<NBLK, 256, 0, stream>>>(feat, out);
}